// Round 4
// baseline (726.923 us; speedup 1.0000x reference)
//
#include <hip/hip_runtime.h>
#include <math.h>
#include <stdint.h>

#define DI __device__ __forceinline__
typedef unsigned short u16;
typedef unsigned int   u32;
typedef unsigned long long u64;

typedef __attribute__((ext_vector_type(4))) float f32x4;
typedef __attribute__((ext_vector_type(8))) short bf16x8;

DI float bf2f(u16 v){ return __uint_as_float(((u32)v) << 16); }
DI u16 f2bf(float f){ u32 u = __float_as_uint(f); return (u16)((u + 0x7FFFu + ((u >> 16) & 1u)) >> 16); }
DI u32 pack2(float re, float im){ return (u32)f2bf(re) | ((u32)f2bf(im) << 16); }

// A&S 7.1.26 erf, |abs err| < 1.5e-7 — much cheaper than libm erff
DI float erf_fast(float x){
  float ax = fabsf(x);
  float t = 1.0f / fmaf(0.3275911f, ax, 1.0f);
  float p = fmaf(t, 1.061405429f, -1.453152027f);
  p = fmaf(t, p, 1.421413741f);
  p = fmaf(t, p, -0.284496736f);
  p = fmaf(t, p, 0.254829592f);
  p *= t;
  float r = 1.0f - p * __expf(-ax * ax);
  return copysignf(r, x);
}

// ---------------- tiled transposes (coalesced both sides) ----------------
__global__ __launch_bounds__(256) void transpose_u32(const u32* __restrict__ in, u32* __restrict__ out, int R, int C){
  __shared__ u32 tile[64][65];
  int t = threadIdx.x;
  int c = t & 63, r0 = t >> 6;
  size_t bofs = (size_t)blockIdx.z * (size_t)R * (size_t)C;
  const u32* ib = in  + bofs + (size_t)(blockIdx.y * 64) * C + blockIdx.x * 64;
  u32*       ob = out + bofs + (size_t)(blockIdx.x * 64) * R + blockIdx.y * 64;
  #pragma unroll
  for (int i = 0; i < 16; i++){ int r = r0 + i * 4; tile[r][c] = ib[(size_t)r * C + c]; }
  __syncthreads();
  #pragma unroll
  for (int i = 0; i < 16; i++){ int r = r0 + i * 4; ob[(size_t)r * R + c] = tile[c][r]; }
}

// fp32 in -> bf16 transposed out (weights: KxN -> NxK bf16)
__global__ __launch_bounds__(256) void transpose_f32_bf16(const float* __restrict__ in, u16* __restrict__ out, int R, int C){
  __shared__ u16 tile[64][65];
  int t = threadIdx.x;
  int c = t & 63, r0 = t >> 6;
  const float* ib = in  + (size_t)(blockIdx.y * 64) * C + blockIdx.x * 64;
  u16*         ob = out + (size_t)(blockIdx.x * 64) * R + blockIdx.y * 64;
  #pragma unroll
  for (int i = 0; i < 16; i++){ int r = r0 + i * 4; tile[r][c] = f2bf(ib[(size_t)r * C + c]); }
  __syncthreads();
  #pragma unroll
  for (int i = 0; i < 16; i++){ int r = r0 + i * 4; ob[(size_t)r * R + c] = tile[c][r]; }
}

// ---------------- radix-4 Stockham FFT in LDS (float2 AoS, b64 DS ops) ----------------
template<int LOGN>
DI float2* fft_r4(float2* s, float2* d, int t){
  const int Q = 1 << (LOGN - 2);
  #pragma unroll
  for (int st = 0; st < (LOGN >> 1); ++st){
    const int m = 1 << (2 * st);
    const float ang = -6.28318530717958647692f * (float)m / (float)(1 << LOGN);
    #pragma unroll
    for (int j0 = 0; j0 < Q; j0 += 256){
      int j = j0 + t;
      int p = j >> (2 * st);
      int q = j & (m - 1);
      int o = q + (p << (2 * st + 2));
      float2 a0 = s[j], a1 = s[j + Q], a2 = s[j + 2 * Q], a3 = s[j + 3 * Q];
      float s0r = a0.x + a2.x, s0i = a0.y + a2.y, d0r = a0.x - a2.x, d0i = a0.y - a2.y;
      float s1r = a1.x + a3.x, s1i = a1.y + a3.y, d1r = a1.x - a3.x, d1i = a1.y - a3.y;
      float sn, cs; __sincosf(ang * (float)p, &sn, &cs);
      float t2r = cs * cs - sn * sn, t2i = 2.f * cs * sn;
      float t3r = t2r * cs - t2i * sn, t3i = t2r * sn + t2i * cs;
      float e1r = d0r + d1i, e1i = d0i - d1r;
      float e2r = s0r - s1r, e2i = s0i - s1i;
      float e3r = d0r - d1i, e3i = d0i + d1r;
      d[o]         = make_float2(s0r + s1r, s0i + s1i);
      d[o + m]     = make_float2(cs * e1r - sn * e1i,  cs * e1i + sn * e1r);
      d[o + 2 * m] = make_float2(t2r * e2r - t2i * e2i, t2r * e2i + t2i * e2r);
      d[o + 3 * m] = make_float2(t3r * e3r - t3i * e3i, t3r * e3i + t3i * e3r);
    }
    __syncthreads();
    float2* tp = s; s = d; d = tp;
  }
  return s;
}

// K1: packed real FFT over seq. Block g handles rows 2g,2g+1 of xT as z=xa+i*xb.
__global__ __launch_bounds__(256) void fft_seq(const float* __restrict__ xT, u32* __restrict__ ZT2,
                                               float* __restrict__ Zny){
  __shared__ float2 A[4096], Bb[4096];  // 64 KB
  int t = threadIdx.x, g = blockIdx.x;  // g in [0,2048)
  const float* r0 = xT + (size_t)(2 * g) * 4096;
  #pragma unroll
  for (int i = 0; i < 4; i++){
    int idx = i * 1024 + t * 4;
    float4 va = *(const float4*)(r0 + idx);
    float4 vb = *(const float4*)(r0 + 4096 + idx);
    A[idx + 0] = make_float2(va.x, vb.x);
    A[idx + 1] = make_float2(va.y, vb.y);
    A[idx + 2] = make_float2(va.z, vb.z);
    A[idx + 3] = make_float2(va.w, vb.w);
  }
  __syncthreads();
  float2* R = fft_r4<12>(A, Bb, t);
  size_t ob0 = (size_t)(2 * g) * 2048;
  #pragma unroll
  for (int i = 0; i < 2; i++){
    int k0 = i * 1024 + t * 4;
    u32 wa[4], wb[4];
    #pragma unroll
    for (int kk = 0; kk < 4; kk++){
      int k = k0 + kk, m = (4096 - k) & 4095;
      float2 zk = R[k], zm = R[m];
      wa[kk] = pack2(0.5f * (zk.x + zm.x), 0.5f * (zk.y - zm.y));   // Xa = (Z+conj(Zm))/2
      wb[kk] = pack2(0.5f * (zk.y + zm.y), 0.5f * (zm.x - zk.x));   // Xb = -i(Z-conj(Zm))/2
    }
    *(uint4*)(ZT2 + ob0 + k0)        = make_uint4(wa[0], wa[1], wa[2], wa[3]);
    *(uint4*)(ZT2 + ob0 + 2048 + k0) = make_uint4(wb[0], wb[1], wb[2], wb[3]);
  }
  if (t == 0){ float2 z = R[2048]; Zny[2 * g] = z.x; Zny[2 * g + 1] = z.y; }
}

DI void block_stats4(float a1, float a2, float b1, float b2, int t,
                     float& mA, float& iA, float& mB, float& iB){
  __shared__ float sh[4][4];
  #pragma unroll
  for (int o = 32; o > 0; o >>= 1){
    a1 += __shfl_down(a1, o); a2 += __shfl_down(a2, o);
    b1 += __shfl_down(b1, o); b2 += __shfl_down(b2, o);
  }
  if ((t & 63) == 0){ int w = t >> 6; sh[w][0] = a1; sh[w][1] = a2; sh[w][2] = b1; sh[w][3] = b2; }
  __syncthreads();
  float SA = sh[0][0] + sh[1][0] + sh[2][0] + sh[3][0];
  float QA = sh[0][1] + sh[1][1] + sh[2][1] + sh[3][1];
  float SB = sh[0][2] + sh[1][2] + sh[2][2] + sh[3][2];
  float QB = sh[0][3] + sh[1][3] + sh[2][3] + sh[3][3];
  mA = SA * (1.f / 1024.f); iA = rsqrtf(QA * (1.f / 1024.f) - mA * mA + 1e-5f);
  mB = SB * (1.f / 1024.f); iB = rsqrtf(QB * (1.f / 1024.f) - mB * mB + 1e-5f);
}

// K2: hidden FFT for k=0..2048 (Hermitian mirror gives row 4096-k), +x residual, LN1 -> h (bf16)
__global__ __launch_bounds__(256) void fft_hid_ln(const u32* __restrict__ Z2, const float* __restrict__ Zny,
    const float* __restrict__ x, const float* __restrict__ g1, const float* __restrict__ be1,
    u16* __restrict__ h){
  __shared__ float2 A[1024], Bb[1024];  // 16 KB
  int t = threadIdx.x, id = blockIdx.x;
  int b = id / 2049, k = id - b * 2049;
  int idx = t * 4;
  if (k == 2048){
    float4 v = *(const float4*)(Zny + b * 1024 + idx);
    A[idx + 0] = make_float2(v.x, 0.f); A[idx + 1] = make_float2(v.y, 0.f);
    A[idx + 2] = make_float2(v.z, 0.f); A[idx + 3] = make_float2(v.w, 0.f);
  } else {
    uint4 zv = *(const uint4*)(Z2 + ((size_t)b * 2048 + k) * 1024 + idx);
    A[idx + 0] = make_float2(bf2f((u16)(zv.x & 0xffffu)), bf2f((u16)(zv.x >> 16)));
    A[idx + 1] = make_float2(bf2f((u16)(zv.y & 0xffffu)), bf2f((u16)(zv.y >> 16)));
    A[idx + 2] = make_float2(bf2f((u16)(zv.z & 0xffffu)), bf2f((u16)(zv.z >> 16)));
    A[idx + 3] = make_float2(bf2f((u16)(zv.w & 0xffffu)), bf2f((u16)(zv.w >> 16)));
  }
  __syncthreads();
  float2* R = fft_r4<10>(A, Bb, t);
  int rowA = b * 4096 + k;
  bool two = (k >= 1) && (k <= 2047);
  int rowB = b * 4096 + (4096 - k);
  float4 xa = *(const float4*)(x + (size_t)rowA * 1024 + idx);
  float vA0 = R[idx + 0].x + xa.x, vA1 = R[idx + 1].x + xa.y;
  float vA2 = R[idx + 2].x + xa.z, vA3 = R[idx + 3].x + xa.w;
  float vB0 = 0.f, vB1 = 0.f, vB2 = 0.f, vB3 = 0.f;
  if (two){
    float4 xb = *(const float4*)(x + (size_t)rowB * 1024 + idx);
    vB0 = R[(1024 - (idx + 0)) & 1023].x + xb.x;   // Re(Y[4096-k,m]) = Re(Y[k,(1024-m)&1023])
    vB1 = R[(1024 - (idx + 1)) & 1023].x + xb.y;
    vB2 = R[(1024 - (idx + 2)) & 1023].x + xb.z;
    vB3 = R[(1024 - (idx + 3)) & 1023].x + xb.w;
  }
  float mA, iA, mB, iB;
  block_stats4(vA0 + vA1 + vA2 + vA3, vA0 * vA0 + vA1 * vA1 + vA2 * vA2 + vA3 * vA3,
               vB0 + vB1 + vB2 + vB3, vB0 * vB0 + vB1 * vB1 + vB2 * vB2 + vB3 * vB3,
               t, mA, iA, mB, iB);
  float4 gv = *(const float4*)(g1 + idx);
  float4 bv = *(const float4*)(be1 + idx);
  ushort4 oA;
  oA.x = f2bf((vA0 - mA) * iA * gv.x + bv.x);
  oA.y = f2bf((vA1 - mA) * iA * gv.y + bv.y);
  oA.z = f2bf((vA2 - mA) * iA * gv.z + bv.z);
  oA.w = f2bf((vA3 - mA) * iA * gv.w + bv.w);
  *(ushort4*)(h + (size_t)rowA * 1024 + idx) = oA;
  if (two){
    ushort4 oB;
    oB.x = f2bf((vB0 - mB) * iB * gv.x + bv.x);
    oB.y = f2bf((vB1 - mB) * iB * gv.y + bv.y);
    oB.z = f2bf((vB2 - mB) * iB * gv.z + bv.z);
    oB.w = f2bf((vB3 - mB) * iB * gv.w + bv.w);
    *(ushort4*)(h + (size_t)rowB * 1024 + idx) = oB;
  }
}

// K3: final LayerNorm on y rows (bf16) -> out (fp32)
__global__ __launch_bounds__(256) void ln_rows(const u16* __restrict__ yv, const float* __restrict__ g,
    const float* __restrict__ be, float* __restrict__ o){
  int t = threadIdx.x;
  size_t base = (size_t)blockIdx.x * 1024;
  int idx = t * 4;
  ushort4 v4 = *(const ushort4*)(yv + base + idx);
  float v0 = bf2f(v4.x), v1 = bf2f(v4.y), v2 = bf2f(v4.z), v3 = bf2f(v4.w);
  float mA, iA, mB, iB;
  block_stats4(v0 + v1 + v2 + v3, v0 * v0 + v1 * v1 + v2 * v2 + v3 * v3, 0.f, 0.f, t, mA, iA, mB, iB);
  float4 gv = *(const float4*)(g + idx);
  float4 bv = *(const float4*)(be + idx);
  float4 ov;
  ov.x = (v0 - mA) * iA * gv.x + bv.x;
  ov.y = (v1 - mA) * iA * gv.y + bv.y;
  ov.z = (v2 - mA) * iA * gv.z + bv.z;
  ov.w = (v3 - mA) * iA * gv.w + bv.w;
  *(float4*)(o + base + idx) = ov;
}

// ---------------- m97-style bf16 GEMM: C = epi(A @ B^T + bias), B given as N x K bf16 ----------------
// 1-D grid, XCD-swizzled: block linear id i -> XCD c=i&7; the NB n-blocks sharing an A-tile get
// consecutive slots on ONE XCD so the A-tile is fetched once into that XCD's L2 (was 8 XCDs = 8 fetches).
// LDS k-chunk XOR swizzle: slot s of row r holds global chunk s^(r&3); fragment reads then spread
// lanes m=0..15 over 8 bank-groups (2-way, free) instead of 2 (8-way).
typedef const __attribute__((address_space(1))) void* as1cp;
typedef __attribute__((address_space(3))) void* as3p;
DI void async_copy16(const void* g, void* l){
  __builtin_amdgcn_global_load_lds((as1cp)(u64)g, (as3p)(u32)(u64)l, 16, 0, 0);
}

template<int DOGELU>
__global__ __launch_bounds__(256) void gemm_bt(const u16* __restrict__ A, const u16* __restrict__ Bm,
    const float* __restrict__ bias, const u16* __restrict__ resid, u16* __restrict__ C,
    int M, int N, int K)
{
  __shared__ u16 As[128 * 32];
  __shared__ u16 Bs[128 * 32];
  int t = threadIdx.x, wv = t >> 6, ln = t & 63;

  int NB = N >> 7;                       // n-blocks
  int bid = blockIdx.x;
  int c8 = bid & 7, j = bid >> 3;
  int nb = j % NB, mg = j / NB;          // requires (M/128) % 8 == 0
  int m0 = (mg * 8 + c8) * 128, n0 = nb * 128;

  const u16* Mat = (wv < 2) ? A : Bm;
  int rb  = (wv < 2) ? m0 : n0;
  u16* Ls = (wv < 2) ? As : Bs;
  int iofs = (wv & 1) * 4;
  int rsub = ln >> 2;                    // row-in-group 0..15
  int ksw  = (ln & 3) ^ (rsub & 3);      // XOR-swizzled k-chunk for staging
  const u16* gp0 = Mat + (size_t)(rb + iofs * 16 + rsub) * K + ksw * 8;
  u16* lp0 = Ls + iofs * 512 + ln * 8;

  f32x4 acc[4][4];
  #pragma unroll
  for (int r = 0; r < 4; r++)
    #pragma unroll
    for (int c = 0; c < 4; c++) acc[r][c] = (f32x4){0.f, 0.f, 0.f, 0.f};

  int wr = wv & 1, wc = wv >> 1;
  int fsl = ((ln >> 4) ^ (ln & 3)) * 8;  // fragment slot after XOR swizzle (row&3 == ln&3)
  const u16* arow = As + (wr * 64 + (ln & 15)) * 32 + fsl;
  const u16* brow = Bs + (wc * 64 + (ln & 15)) * 32 + fsl;

  for (int k0 = 0; k0 < K; k0 += 32){
    #pragma unroll
    for (int ii = 0; ii < 4; ii++)
      async_copy16(gp0 + (size_t)ii * 16 * K + k0, lp0 + ii * 512);
    __syncthreads();
    bf16x8 af[4], bfr[4];
    #pragma unroll
    for (int r = 0; r < 4; r++) af[r]  = *(const bf16x8*)(arow + r * 512);
    #pragma unroll
    for (int c = 0; c < 4; c++) bfr[c] = *(const bf16x8*)(brow + c * 512);
    #pragma unroll
    for (int r = 0; r < 4; r++)
      #pragma unroll
      for (int c = 0; c < 4; c++)
        acc[r][c] = __builtin_amdgcn_mfma_f32_16x16x32_bf16(af[r], bfr[c], acc[r][c], 0, 0, 0);
    __syncthreads();
  }

  int colq = ln & 15, rq = ln >> 4;
  #pragma unroll
  for (int r = 0; r < 4; r++){
    int mr = m0 + wr * 64 + r * 16 + rq * 4;
    #pragma unroll
    for (int c = 0; c < 4; c++){
      int col = n0 + wc * 64 + c * 16 + colq;
      float bv = bias[col];
      #pragma unroll
      for (int i = 0; i < 4; i++){
        float v = acc[r][c][i] + bv;
        if (DOGELU){
          v = 0.5f * v * (1.0f + erf_fast(v * 0.70710678118654752440f));  // exact GELU (A&S erf)
        } else {
          v += bf2f(resid[(size_t)(mr + i) * N + col]);
        }
        C[(size_t)(mr + i) * N + col] = f2bf(v);
      }
    }
  }
}

// ---------------- orchestration ----------------
// B=4, S=4096, H=1024, fp32 I/O. ws >= 209 MiB proven (round-3 FETCH signature => nch=1 ran).
extern "C" void kernel_launch(void* const* d_in, const int* in_sizes, int n_in,
                              void* d_out, int out_size, void* d_ws, size_t ws_size,
                              hipStream_t stream){
  const float* x   = (const float*)d_in[0];
  const float* w1  = (const float*)d_in[1];
  const float* b1  = (const float*)d_in[2];
  const float* w2  = (const float*)d_in[3];
  const float* b2  = (const float*)d_in[4];
  const float* g1  = (const float*)d_in[5];
  const float* be1 = (const float*)d_in[6];
  const float* g2  = (const float*)d_in[7];
  const float* be2 = (const float*)d_in[8];
  float* out = (float*)d_out;
  char* ws = (char*)d_ws;
  const size_t MB = (size_t)1 << 20;
  float* xT  = (float*)(ws);
  u32*  ZT2  = (u32*)(ws + 64 * MB);
  float* Zny = (float*)(ws + 96 * MB);
  u32*  Z2   = (u32*)(ws);
  u16*  h    = (u16*)(ws + 32 * MB);
  u16*  w1T  = (u16*)(ws + 64 * MB);
  u16*  w2T  = (u16*)(ws + 72 * MB);
  u16*  u    = (u16*)(ws + 80 * MB);
  u16*  y    = (u16*)(ws);
  dim3 blk(256, 1, 1);

  // mixing: seq FFT (packed real pairs) -> Hermitian half -> hidden FFT (+x, LN1)
  transpose_u32<<<dim3(16, 64, 4), blk, 0, stream>>>((const u32*)x, (u32*)xT, 4096, 1024);
  fft_seq      <<<dim3(2048, 1, 1), blk, 0, stream>>>(xT, ZT2, Zny);
  transpose_u32<<<dim3(32, 16, 4), blk, 0, stream>>>(ZT2, Z2, 1024, 2048);
  fft_hid_ln   <<<dim3(4 * 2049, 1, 1), blk, 0, stream>>>(Z2, Zny, x, g1, be1, h);

  // FFN
  transpose_f32_bf16<<<dim3(64, 16, 1), blk, 0, stream>>>(w1, w1T, 1024, 4096);
  transpose_f32_bf16<<<dim3(16, 64, 1), blk, 0, stream>>>(w2, w2T, 4096, 1024);
  int nch = (ws_size >= (size_t)209 * MB) ? 1 : (ws_size >= (size_t)145 * MB) ? 2 : 4;
  int Mc = 16384 / nch;
  for (int ch = 0; ch < nch; ++ch){
    const u16* hch = h + (size_t)ch * Mc * 1024;
    u16* ych = y + (size_t)ch * Mc * 1024;
    gemm_bt<1><<<dim3(32 * (Mc / 128)), blk, 0, stream>>>(hch, w1T, b1, (const u16*)nullptr, u, Mc, 4096, 1024);
    gemm_bt<0><<<dim3(8  * (Mc / 128)), blk, 0, stream>>>(u, w2T, b2, hch, ych, Mc, 1024, 4096);
  }
  ln_rows<<<dim3(16384, 1, 1), blk, 0, stream>>>(y, g2, be2, out);
}

// Round 5
// 679.050 us; speedup vs baseline: 1.0705x; 1.0705x over previous
//
#include <hip/hip_runtime.h>
#include <math.h>
#include <stdint.h>

#define DI __device__ __forceinline__
typedef unsigned short u16;
typedef unsigned int   u32;
typedef unsigned long long u64;

typedef __attribute__((ext_vector_type(4))) float f32x4;
typedef __attribute__((ext_vector_type(8))) short bf16x8;

DI float bf2f(u16 v){ return __uint_as_float(((u32)v) << 16); }
DI u16 f2bf(float f){ u32 u = __float_as_uint(f); return (u16)((u + 0x7FFFu + ((u >> 16) & 1u)) >> 16); }
DI u32 pack2(float re, float im){ return (u32)f2bf(re) | ((u32)f2bf(im) << 16); }

// tanh-form GELU: v*sigmoid(2z), z = sqrt(2/pi)(v+0.044715v^3). Max |err| vs exact
// erf-GELU ~5e-4 (budget 0.11). ~9 VALU incl one v_exp. z clamped: exp overflow guard.
DI float gelu_fast(float v){
  float t = v * v;
  float z = v * fmaf(0.0356774081f, t, 0.7978845608f);
  z = fminf(z, 15.0f);
  float e = __expf(2.0f * z);
  return v * e * __frcp_rn(1.0f + e);
}

// ---------------- tiled transposes (coalesced both sides) ----------------
__global__ __launch_bounds__(256) void transpose_u32(const u32* __restrict__ in, u32* __restrict__ out, int R, int C){
  __shared__ u32 tile[64][65];
  int t = threadIdx.x;
  int c = t & 63, r0 = t >> 6;
  size_t bofs = (size_t)blockIdx.z * (size_t)R * (size_t)C;
  const u32* ib = in  + bofs + (size_t)(blockIdx.y * 64) * C + blockIdx.x * 64;
  u32*       ob = out + bofs + (size_t)(blockIdx.x * 64) * R + blockIdx.y * 64;
  #pragma unroll
  for (int i = 0; i < 16; i++){ int r = r0 + i * 4; tile[r][c] = ib[(size_t)r * C + c]; }
  __syncthreads();
  #pragma unroll
  for (int i = 0; i < 16; i++){ int r = r0 + i * 4; ob[(size_t)r * R + c] = tile[c][r]; }
}

// fp32 in -> bf16 transposed out (weights: KxN -> NxK bf16)
__global__ __launch_bounds__(256) void transpose_f32_bf16(const float* __restrict__ in, u16* __restrict__ out, int R, int C){
  __shared__ u16 tile[64][65];
  int t = threadIdx.x;
  int c = t & 63, r0 = t >> 6;
  const float* ib = in  + (size_t)(blockIdx.y * 64) * C + blockIdx.x * 64;
  u16*         ob = out + (size_t)(blockIdx.x * 64) * R + blockIdx.y * 64;
  #pragma unroll
  for (int i = 0; i < 16; i++){ int r = r0 + i * 4; tile[r][c] = f2bf(ib[(size_t)r * C + c]); }
  __syncthreads();
  #pragma unroll
  for (int i = 0; i < 16; i++){ int r = r0 + i * 4; ob[(size_t)r * R + c] = tile[c][r]; }
}

// ---------------- radix-4 Stockham FFT in LDS (float2 AoS, b64 DS ops) ----------------
template<int LOGN>
DI float2* fft_r4(float2* s, float2* d, int t){
  const int Q = 1 << (LOGN - 2);
  #pragma unroll
  for (int st = 0; st < (LOGN >> 1); ++st){
    const int m = 1 << (2 * st);
    const float ang = -6.28318530717958647692f * (float)m / (float)(1 << LOGN);
    #pragma unroll
    for (int j0 = 0; j0 < Q; j0 += 256){
      int j = j0 + t;
      int p = j >> (2 * st);
      int q = j & (m - 1);
      int o = q + (p << (2 * st + 2));
      float2 a0 = s[j], a1 = s[j + Q], a2 = s[j + 2 * Q], a3 = s[j + 3 * Q];
      float s0r = a0.x + a2.x, s0i = a0.y + a2.y, d0r = a0.x - a2.x, d0i = a0.y - a2.y;
      float s1r = a1.x + a3.x, s1i = a1.y + a3.y, d1r = a1.x - a3.x, d1i = a1.y - a3.y;
      float sn, cs; __sincosf(ang * (float)p, &sn, &cs);
      float t2r = cs * cs - sn * sn, t2i = 2.f * cs * sn;
      float t3r = t2r * cs - t2i * sn, t3i = t2r * sn + t2i * cs;
      float e1r = d0r + d1i, e1i = d0i - d1r;
      float e2r = s0r - s1r, e2i = s0i - s1i;
      float e3r = d0r - d1i, e3i = d0i + d1r;
      d[o]         = make_float2(s0r + s1r, s0i + s1i);
      d[o + m]     = make_float2(cs * e1r - sn * e1i,  cs * e1i + sn * e1r);
      d[o + 2 * m] = make_float2(t2r * e2r - t2i * e2i, t2r * e2i + t2i * e2r);
      d[o + 3 * m] = make_float2(t3r * e3r - t3i * e3i, t3r * e3i + t3i * e3r);
    }
    __syncthreads();
    float2* tp = s; s = d; d = tp;
  }
  return s;
}

// K1: packed real FFT over seq. Block g handles rows 2g,2g+1 of xT as z=xa+i*xb.
__global__ __launch_bounds__(256) void fft_seq(const float* __restrict__ xT, u32* __restrict__ ZT2,
                                               float* __restrict__ Zny){
  __shared__ float2 A[4096], Bb[4096];  // 64 KB
  int t = threadIdx.x, g = blockIdx.x;  // g in [0,2048)
  const float* r0 = xT + (size_t)(2 * g) * 4096;
  #pragma unroll
  for (int i = 0; i < 4; i++){
    int idx = i * 1024 + t * 4;
    float4 va = *(const float4*)(r0 + idx);
    float4 vb = *(const float4*)(r0 + 4096 + idx);
    A[idx + 0] = make_float2(va.x, vb.x);
    A[idx + 1] = make_float2(va.y, vb.y);
    A[idx + 2] = make_float2(va.z, vb.z);
    A[idx + 3] = make_float2(va.w, vb.w);
  }
  __syncthreads();
  float2* R = fft_r4<12>(A, Bb, t);
  size_t ob0 = (size_t)(2 * g) * 2048;
  #pragma unroll
  for (int i = 0; i < 2; i++){
    int k0 = i * 1024 + t * 4;
    u32 wa[4], wb[4];
    #pragma unroll
    for (int kk = 0; kk < 4; kk++){
      int k = k0 + kk, m = (4096 - k) & 4095;
      float2 zk = R[k], zm = R[m];
      wa[kk] = pack2(0.5f * (zk.x + zm.x), 0.5f * (zk.y - zm.y));   // Xa = (Z+conj(Zm))/2
      wb[kk] = pack2(0.5f * (zk.y + zm.y), 0.5f * (zm.x - zk.x));   // Xb = -i(Z-conj(Zm))/2
    }
    *(uint4*)(ZT2 + ob0 + k0)        = make_uint4(wa[0], wa[1], wa[2], wa[3]);
    *(uint4*)(ZT2 + ob0 + 2048 + k0) = make_uint4(wb[0], wb[1], wb[2], wb[3]);
  }
  if (t == 0){ float2 z = R[2048]; Zny[2 * g] = z.x; Zny[2 * g + 1] = z.y; }
}

DI void block_stats4(float a1, float a2, float b1, float b2, int t,
                     float& mA, float& iA, float& mB, float& iB){
  __shared__ float sh[4][4];
  #pragma unroll
  for (int o = 32; o > 0; o >>= 1){
    a1 += __shfl_down(a1, o); a2 += __shfl_down(a2, o);
    b1 += __shfl_down(b1, o); b2 += __shfl_down(b2, o);
  }
  if ((t & 63) == 0){ int w = t >> 6; sh[w][0] = a1; sh[w][1] = a2; sh[w][2] = b1; sh[w][3] = b2; }
  __syncthreads();
  float SA = sh[0][0] + sh[1][0] + sh[2][0] + sh[3][0];
  float QA = sh[0][1] + sh[1][1] + sh[2][1] + sh[3][1];
  float SB = sh[0][2] + sh[1][2] + sh[2][2] + sh[3][2];
  float QB = sh[0][3] + sh[1][3] + sh[2][3] + sh[3][3];
  mA = SA * (1.f / 1024.f); iA = rsqrtf(QA * (1.f / 1024.f) - mA * mA + 1e-5f);
  mB = SB * (1.f / 1024.f); iB = rsqrtf(QB * (1.f / 1024.f) - mB * mB + 1e-5f);
}

// K2: hidden FFT for k=0..2048 (Hermitian mirror gives row 4096-k), +x residual, LN1 -> h (bf16)
__global__ __launch_bounds__(256) void fft_hid_ln(const u32* __restrict__ Z2, const float* __restrict__ Zny,
    const float* __restrict__ x, const float* __restrict__ g1, const float* __restrict__ be1,
    u16* __restrict__ h){
  __shared__ float2 A[1024], Bb[1024];  // 16 KB
  int t = threadIdx.x, id = blockIdx.x;
  int b = id / 2049, k = id - b * 2049;
  int idx = t * 4;
  if (k == 2048){
    float4 v = *(const float4*)(Zny + b * 1024 + idx);
    A[idx + 0] = make_float2(v.x, 0.f); A[idx + 1] = make_float2(v.y, 0.f);
    A[idx + 2] = make_float2(v.z, 0.f); A[idx + 3] = make_float2(v.w, 0.f);
  } else {
    uint4 zv = *(const uint4*)(Z2 + ((size_t)b * 2048 + k) * 1024 + idx);
    A[idx + 0] = make_float2(bf2f((u16)(zv.x & 0xffffu)), bf2f((u16)(zv.x >> 16)));
    A[idx + 1] = make_float2(bf2f((u16)(zv.y & 0xffffu)), bf2f((u16)(zv.y >> 16)));
    A[idx + 2] = make_float2(bf2f((u16)(zv.z & 0xffffu)), bf2f((u16)(zv.z >> 16)));
    A[idx + 3] = make_float2(bf2f((u16)(zv.w & 0xffffu)), bf2f((u16)(zv.w >> 16)));
  }
  __syncthreads();
  float2* R = fft_r4<10>(A, Bb, t);
  int rowA = b * 4096 + k;
  bool two = (k >= 1) && (k <= 2047);
  int rowB = b * 4096 + (4096 - k);
  float4 xa = *(const float4*)(x + (size_t)rowA * 1024 + idx);
  float vA0 = R[idx + 0].x + xa.x, vA1 = R[idx + 1].x + xa.y;
  float vA2 = R[idx + 2].x + xa.z, vA3 = R[idx + 3].x + xa.w;
  float vB0 = 0.f, vB1 = 0.f, vB2 = 0.f, vB3 = 0.f;
  if (two){
    float4 xb = *(const float4*)(x + (size_t)rowB * 1024 + idx);
    vB0 = R[(1024 - (idx + 0)) & 1023].x + xb.x;   // Re(Y[4096-k,m]) = Re(Y[k,(1024-m)&1023])
    vB1 = R[(1024 - (idx + 1)) & 1023].x + xb.y;
    vB2 = R[(1024 - (idx + 2)) & 1023].x + xb.z;
    vB3 = R[(1024 - (idx + 3)) & 1023].x + xb.w;
  }
  float mA, iA, mB, iB;
  block_stats4(vA0 + vA1 + vA2 + vA3, vA0 * vA0 + vA1 * vA1 + vA2 * vA2 + vA3 * vA3,
               vB0 + vB1 + vB2 + vB3, vB0 * vB0 + vB1 * vB1 + vB2 * vB2 + vB3 * vB3,
               t, mA, iA, mB, iB);
  float4 gv = *(const float4*)(g1 + idx);
  float4 bv = *(const float4*)(be1 + idx);
  ushort4 oA;
  oA.x = f2bf((vA0 - mA) * iA * gv.x + bv.x);
  oA.y = f2bf((vA1 - mA) * iA * gv.y + bv.y);
  oA.z = f2bf((vA2 - mA) * iA * gv.z + bv.z);
  oA.w = f2bf((vA3 - mA) * iA * gv.w + bv.w);
  *(ushort4*)(h + (size_t)rowA * 1024 + idx) = oA;
  if (two){
    ushort4 oB;
    oB.x = f2bf((vB0 - mB) * iB * gv.x + bv.x);
    oB.y = f2bf((vB1 - mB) * iB * gv.y + bv.y);
    oB.z = f2bf((vB2 - mB) * iB * gv.z + bv.z);
    oB.w = f2bf((vB3 - mB) * iB * gv.w + bv.w);
    *(ushort4*)(h + (size_t)rowB * 1024 + idx) = oB;
  }
}

// K3: final LayerNorm on y rows (bf16) -> out (fp32)
__global__ __launch_bounds__(256) void ln_rows(const u16* __restrict__ yv, const float* __restrict__ g,
    const float* __restrict__ be, float* __restrict__ o){
  int t = threadIdx.x;
  size_t base = (size_t)blockIdx.x * 1024;
  int idx = t * 4;
  ushort4 v4 = *(const ushort4*)(yv + base + idx);
  float v0 = bf2f(v4.x), v1 = bf2f(v4.y), v2 = bf2f(v4.z), v3 = bf2f(v4.w);
  float mA, iA, mB, iB;
  block_stats4(v0 + v1 + v2 + v3, v0 * v0 + v1 * v1 + v2 * v2 + v3 * v3, 0.f, 0.f, t, mA, iA, mB, iB);
  float4 gv = *(const float4*)(g + idx);
  float4 bv = *(const float4*)(be + idx);
  float4 ov;
  ov.x = (v0 - mA) * iA * gv.x + bv.x;
  ov.y = (v1 - mA) * iA * gv.y + bv.y;
  ov.z = (v2 - mA) * iA * gv.z + bv.z;
  ov.w = (v3 - mA) * iA * gv.w + bv.w;
  *(float4*)(o + base + idx) = ov;
}

// ---------------- m97-style bf16 GEMM: C = epi(A @ B^T + bias), B given as N x K bf16 ----------------
// XCD partition (bid%8 -> XCD heuristic): 8 XCDs = 4 n-groups x 2 m-halves.
// Each XCD's B working set = (NB/4) tiles (<=2 MB) -> L2-resident across its whole m-sweep;
// each A-tile is read by only the 4 n-group XCDs of its m-half (L3 absorbs).
// n sweeps fastest within an XCD so B-tiles lock into L2 after the first m-row.
typedef const __attribute__((address_space(1))) void* as1cp;
typedef __attribute__((address_space(3))) void* as3p;
DI void async_copy16(const void* g, void* l){
  __builtin_amdgcn_global_load_lds((as1cp)(u64)g, (as3p)(u32)(u64)l, 16, 0, 0);
}

template<int DOGELU>
__global__ __launch_bounds__(256) void gemm_bt(const u16* __restrict__ A, const u16* __restrict__ Bm,
    const float* __restrict__ bias, const u16* __restrict__ resid, u16* __restrict__ C,
    int M, int N, int K, int npg_shift)
{
  __shared__ u16 As[128 * 32];
  __shared__ u16 Bs[128 * 32];
  int t = threadIdx.x, wv = t >> 6, ln = t & 63;

  int bid = blockIdx.x;
  int c8 = bid & 7, j = bid >> 3;
  int ng = c8 & 3, mh = c8 >> 2;
  int npg = 1 << npg_shift;              // n-tiles per group = NB/4
  int mph = M >> 8;                      // m-tiles per half  = (M/128)/2
  int n0 = ((ng << npg_shift) + (j & (npg - 1))) << 7;
  int m0 = (mh * mph + (j >> npg_shift)) << 7;

  const u16* Mat = (wv < 2) ? A : Bm;
  int rb  = (wv < 2) ? m0 : n0;
  u16* Ls = (wv < 2) ? As : Bs;
  int iofs = (wv & 1) * 4;
  const u16* gp0 = Mat + (size_t)(rb + iofs * 16 + (ln >> 2)) * K + (ln & 3) * 8;
  u16* lp0 = Ls + iofs * 512 + ln * 8;

  f32x4 acc[4][4];
  #pragma unroll
  for (int r = 0; r < 4; r++)
    #pragma unroll
    for (int c = 0; c < 4; c++) acc[r][c] = (f32x4){0.f, 0.f, 0.f, 0.f};

  int wr = wv & 1, wc = wv >> 1;
  const u16* arow = As + (wr * 64 + (ln & 15)) * 32 + (ln >> 4) * 8;
  const u16* brow = Bs + (wc * 64 + (ln & 15)) * 32 + (ln >> 4) * 8;

  for (int k0 = 0; k0 < K; k0 += 32){
    #pragma unroll
    for (int ii = 0; ii < 4; ii++)
      async_copy16(gp0 + (size_t)ii * 16 * K + k0, lp0 + ii * 512);
    __syncthreads();
    bf16x8 af[4], bfr[4];
    #pragma unroll
    for (int r = 0; r < 4; r++) af[r]  = *(const bf16x8*)(arow + r * 512);
    #pragma unroll
    for (int c = 0; c < 4; c++) bfr[c] = *(const bf16x8*)(brow + c * 512);
    #pragma unroll
    for (int r = 0; r < 4; r++)
      #pragma unroll
      for (int c = 0; c < 4; c++)
        acc[r][c] = __builtin_amdgcn_mfma_f32_16x16x32_bf16(af[r], bfr[c], acc[r][c], 0, 0, 0);
    __syncthreads();
  }

  // epilogue: D[m][n], col = lane&15, row = (lane>>4)*4 + reg   [m89-verified mapping]
  int colq = ln & 15, rq = ln >> 4;
  #pragma unroll
  for (int r = 0; r < 4; r++){
    int mr = m0 + wr * 64 + r * 16 + rq * 4;
    #pragma unroll
    for (int c = 0; c < 4; c++){
      int col = n0 + wc * 64 + c * 16 + colq;
      float bv = bias[col];
      #pragma unroll
      for (int i = 0; i < 4; i++){
        float v = acc[r][c][i] + bv;
        if (DOGELU){
          v = gelu_fast(v);
        } else {
          v += bf2f(resid[(size_t)(mr + i) * N + col]);
        }
        C[(size_t)(mr + i) * N + col] = f2bf(v);
      }
    }
  }
}

// ---------------- orchestration ----------------
// B=4, S=4096, H=1024, fp32 I/O. ws >= 209 MiB proven (round-3 nch=1 FETCH signature).
extern "C" void kernel_launch(void* const* d_in, const int* in_sizes, int n_in,
                              void* d_out, int out_size, void* d_ws, size_t ws_size,
                              hipStream_t stream){
  const float* x   = (const float*)d_in[0];
  const float* w1  = (const float*)d_in[1];
  const float* b1  = (const float*)d_in[2];
  const float* w2  = (const float*)d_in[3];
  const float* b2  = (const float*)d_in[4];
  const float* g1  = (const float*)d_in[5];
  const float* be1 = (const float*)d_in[6];
  const float* g2  = (const float*)d_in[7];
  const float* be2 = (const float*)d_in[8];
  float* out = (float*)d_out;
  char* ws = (char*)d_ws;
  const size_t MB = (size_t)1 << 20;
  float* xT  = (float*)(ws);
  u32*  ZT2  = (u32*)(ws + 64 * MB);
  float* Zny = (float*)(ws + 96 * MB);
  u32*  Z2   = (u32*)(ws);
  u16*  h    = (u16*)(ws + 32 * MB);
  u16*  w1T  = (u16*)(ws + 64 * MB);
  u16*  w2T  = (u16*)(ws + 72 * MB);
  u16*  u    = (u16*)(ws + 80 * MB);
  u16*  y    = (u16*)(ws);
  dim3 blk(256, 1, 1);

  // mixing: seq FFT (packed real pairs) -> Hermitian half -> hidden FFT (+x, LN1)
  transpose_u32<<<dim3(16, 64, 4), blk, 0, stream>>>((const u32*)x, (u32*)xT, 4096, 1024);
  fft_seq      <<<dim3(2048, 1, 1), blk, 0, stream>>>(xT, ZT2, Zny);
  transpose_u32<<<dim3(32, 16, 4), blk, 0, stream>>>(ZT2, Z2, 1024, 2048);
  fft_hid_ln   <<<dim3(4 * 2049, 1, 1), blk, 0, stream>>>(Z2, Zny, x, g1, be1, h);

  // FFN
  transpose_f32_bf16<<<dim3(64, 16, 1), blk, 0, stream>>>(w1, w1T, 1024, 4096);
  transpose_f32_bf16<<<dim3(16, 64, 1), blk, 0, stream>>>(w2, w2T, 4096, 1024);
  int nch = (ws_size >= (size_t)209 * MB) ? 1 : (ws_size >= (size_t)145 * MB) ? 2 : 4;
  int Mc = 16384 / nch;
  for (int ch = 0; ch < nch; ++ch){
    const u16* hch = h + (size_t)ch * Mc * 1024;
    u16* ych = y + (size_t)ch * Mc * 1024;
    gemm_bt<1><<<dim3(32 * (Mc / 128)), blk, 0, stream>>>(hch, w1T, b1, (const u16*)nullptr, u, Mc, 4096, 1024, 3);
    gemm_bt<0><<<dim3(8  * (Mc / 128)), blk, 0, stream>>>(u, w2T, b2, hch, ych, Mc, 1024, 4096, 1);
  }
  ln_rows<<<dim3(16384, 1, 1), blk, 0, stream>>>(y, g2, be2, out);
}